// Round 7
// baseline (1230.150 us; speedup 1.0000x reference)
//
#include <hip/hip_runtime.h>
#include <hip/hip_bf16.h>

#define CHW  65536   // 16 ch * 64 * 64 per bg-group
#define CHW4 16384   // in float4

__device__ __forceinline__ float wred(float v){
#pragma unroll
  for (int o = 32; o; o >>= 1) v += __shfl_xor(v, o, 64);
  return v;
}
__device__ __forceinline__ float bf2f(unsigned short u){
  return __uint_as_float(((unsigned)u) << 16);
}
__device__ __forceinline__ unsigned short f2b(float f){
  union { __hip_bfloat16 h; unsigned short u; } cv;
  cv.h = __float2bfloat16(f);
  return cv.u;
}

// ---------------- K3: 3x3 grouped conv, ZERO LDS ----------------------------
// Each thread computes 8 px of one output row for 4 co; input rows come
// straight from global (L1/L2-cached; per-ci slab ~2.8 KB, all 4 waves sweep
// ci in lockstep -> halo redundancy served by L1, not the conflict-prone LDS
// pipe).  Also emits pooled row/col-sum partials (wave ci&3 owns ci) and
// V3/Z3 stripe partials + E3 = exp(relu(x3)) bf16.
__global__ __launch_bounds__(256, 5) void k3_conv(const float* __restrict__ x,
    const float* __restrict__ w3, const float* __restrict__ b3,
    __hip_bfloat16* __restrict__ E3,
    float* __restrict__ V3part, float* __restrict__ Z3part,
    float* __restrict__ rs_g, float* __restrict__ csp_g)
{
  int tid = threadIdx.x;
  int st  = blockIdx.x;      // stripe 0..7
  int bg  = blockIdx.y;
  size_t base  = (size_t)bg * CHW;
  const float4* x4 = (const float4*)x + (size_t)bg * CHW4;
  int lane = tid & 63;
  int cog = __builtin_amdgcn_readfirstlane(tid >> 6);  // wave-uniform co group
  int co0 = cog * 4;
  int r  = lane >> 3;          // output row within stripe
  int cc = lane & 7;           // 8-px col chunk
  int h0 = st*8 + r;           // output row in image
  int sl0 = cc*2;              // base float4 slot (w0/4)

  float acc[4][8];
#pragma unroll
  for (int i = 0; i < 4; ++i)
#pragma unroll
    for (int px = 0; px < 8; ++px) acc[i][px] = 0.f;

  const float4 z4 = make_float4(0.f, 0.f, 0.f, 0.f);

#pragma unroll 1
  for (int ci = 0; ci < 16; ++ci){
    // ---- direct loads: 3 rows x 4 slots (cols w0-4 .. w0+11) ----
    float4 R[3][4];
#pragma unroll
    for (int dy = 0; dy < 3; ++dy){
      int hh = h0 - 1 + dy;
      bool rok = (unsigned)hh < 64u;
      const float4* rp = &x4[ci*1024 + hh*16];
      R[dy][0] = (rok && cc > 0) ? rp[sl0-1] : z4;
      R[dy][1] = rok ? rp[sl0]   : z4;
      R[dy][2] = rok ? rp[sl0+1] : z4;
      R[dy][3] = (rok && cc < 7) ? rp[sl0+2] : z4;
    }
    // ---- weights (wave-uniform -> scalar loads) ----
    float wgt[4][9];
#pragma unroll
    for (int i = 0; i < 4; ++i)
#pragma unroll
      for (int t = 0; t < 9; ++t)
        wgt[i][t] = w3[((co0+i)*16 + ci)*9 + t];
    // ---- FMAs ----
#pragma unroll
    for (int dy = 0; dy < 3; ++dy){
      float v[16] = {R[dy][0].x,R[dy][0].y,R[dy][0].z,R[dy][0].w,
                     R[dy][1].x,R[dy][1].y,R[dy][1].z,R[dy][1].w,
                     R[dy][2].x,R[dy][2].y,R[dy][2].z,R[dy][2].w,
                     R[dy][3].x,R[dy][3].y,R[dy][3].z,R[dy][3].w};
#pragma unroll
      for (int dx = 0; dx < 3; ++dx){
#pragma unroll
        for (int px = 0; px < 8; ++px){
          float iv = v[px + dx + 3];
#pragma unroll
          for (int i = 0; i < 4; ++i)
            acc[i][px] = fmaf(wgt[i][dy*3+dx], iv, acc[i][px]);
        }
      }
    }
    // ---- pooled partials from center-row registers (wave ci&3 owns ci) ----
    if (cog == (ci & 3)){
      // row sum: this thread's 8 px of row h0
      float sm = R[1][1].x+R[1][1].y+R[1][1].z+R[1][1].w
               + R[1][2].x+R[1][2].y+R[1][2].z+R[1][2].w;
      sm += __shfl_xor(sm, 1, 64);
      sm += __shfl_xor(sm, 2, 64);
      sm += __shfl_xor(sm, 4, 64);
      if (cc == 0) rs_g[(size_t)bg*1024 + ci*64 + h0] = sm;
      // col sums over this stripe's 8 rows (reduce across r = stride-8 lanes)
      float4 ca = R[1][1], cb = R[1][2];
#pragma unroll
      for (int o = 8; o < 64; o <<= 1){
        ca.x += __shfl_xor(ca.x, o, 64); ca.y += __shfl_xor(ca.y, o, 64);
        ca.z += __shfl_xor(ca.z, o, 64); ca.w += __shfl_xor(ca.w, o, 64);
        cb.x += __shfl_xor(cb.x, o, 64); cb.y += __shfl_xor(cb.y, o, 64);
        cb.z += __shfl_xor(cb.z, o, 64); cb.w += __shfl_xor(cb.w, o, 64);
      }
      if (r == 0){
        float* cp = &csp_g[((size_t)(bg*8 + st)*16 + ci)*64 + cc*8];
        *(float4*)&cp[0] = ca;
        *(float4*)&cp[4] = cb;
      }
    }
  }

  // ---- epilogue: relu/exp -> E3 bf16, V3/Z3 stripe partials ----
#pragma unroll
  for (int i = 0; i < 4; ++i){
    float bias = b3[co0+i];
    union { unsigned short hb[8]; uint4 u; } pk;
    float v3acc = 0.f, z3acc = 0.f;
#pragma unroll
    for (int px = 0; px < 8; ++px){
      float val = fmaxf(acc[i][px] + bias, 0.f);   // x3
      float e = __expf(val);
      v3acc += val;
      z3acc += e;
      pk.hb[px] = f2b(e);
    }
    *(uint4*)&E3[base + (size_t)(co0+i)*4096 + h0*64 + cc*8] = pk.u;
    float rv = wred(v3acc);
    float rz = wred(z3acc);
    if (lane == 0){
      V3part[((size_t)bg*8 + st)*16 + co0 + i] = rv;
      Z3part[((size_t)bg*8 + st)*16 + co0 + i] = rz;
    }
  }
}

// ---------------- MEGA: attention maps + stats + t softmax + out ------------
// pass0 x-sweep replaced by reading k3's pooled partials; passC reads no x
// (exp(x2) carried bf16-packed in registers from passB).
__global__ __launch_bounds__(1024, 8) void mega(const float* __restrict__ x,
    const float* __restrict__ w1, const float* __restrict__ b1,
    const float* __restrict__ wh, const float* __restrict__ bh,
    const float* __restrict__ ww, const float* __restrict__ bw,
    const float* __restrict__ gnw, const float* __restrict__ gnb,
    const float* __restrict__ V3part, const float* __restrict__ Z3part,
    const float* __restrict__ rs_g, const float* __restrict__ csp_g,
    const __hip_bfloat16* __restrict__ E3,
    float* __restrict__ out)
{
  __shared__ float rs[1024];                 // rowsum[ch*64+h]
  __shared__ float cs[1024];                 // colsum[ch*64+w]
  __shared__ float ym[2048];
  __shared__ __align__(16) float ahs[1024], aws[1024];
  __shared__ float chpart[256], zpart[256];
  __shared__ float red1[16], red2[16];
  __shared__ float murs[2];
  __shared__ float sc_s[16], of_s[16], v2_s[16], p2s[16], p3s[16];
  __shared__ float invS_s;

  int tid = threadIdx.x, bg = blockIdx.x;
  const float4* x4 = (const float4*)x + (size_t)bg * CHW4;
  const ushort4* E34 = (const ushort4*)E3 + (size_t)bg * CHW4;
  float4* o4 = (float4*)out + (size_t)bg * CHW4;
  int h = tid >> 4, w4 = tid & 15, lane = tid & 63, wv = tid >> 6;

  // ---- pass 0': pooled sums from k3 partials (no x sweep) ----
  rs[tid] = rs_g[(size_t)bg*1024 + tid];
  {
    const float* cp = csp_g + (size_t)bg*8192;
    float csum = 0.f;
#pragma unroll
    for (int ss = 0; ss < 8; ++ss) csum += cp[ss*1024 + tid];
    cs[tid] = csum;
  }
  __syncthreads();
  // y = relu(w1 @ [rowmean|colmean] + b1)
  for (int ol = tid; ol < 2048; ol += 1024){
    int o = ol >> 7, l = ol & 127;
    float acc = b1[o];
#pragma unroll
    for (int i = 0; i < 16; ++i){
      float mv = (l < 64 ? rs[i*64 + l] : cs[i*64 + (l-64)]) * (1.f/64.f);
      acc = fmaf(w1[o*16 + i], mv, acc);
    }
    ym[o*128 + l] = fmaxf(acc, 0.f);
  }
  __syncthreads();
  for (int ol = tid; ol < 2048; ol += 1024){
    int q = ol >> 10;             // 0 -> a_h, 1 -> a_w
    int o = (ol >> 6) & 15;
    int p = ol & 63;
    const float* Wm = q ? ww : wh;
    float acc = q ? bw[o] : bh[o];
#pragma unroll
    for (int i = 0; i < 16; ++i)
      acc = fmaf(Wm[o*16 + i], ym[i*128 + q*64 + p], acc);
    float sg = 1.f / (1.f + __expf(-acc));
    (q ? aws : ahs)[o*64 + p] = sg;
  }
  __syncthreads();

  // ---- pass A: mu/var + per-channel sums ----
  const float4* aws4 = (const float4*)aws;
  float s1 = 0.f, s2 = 0.f;
#pragma unroll 4
  for (int k = 0; k < 16; ++k){
    float4 v = x4[k*1024 + tid];
    float ah = ahs[k*64 + h];
    float4 aw = aws4[k*16 + w4];
    float4 x1;
    x1.x = v.x * ah * aw.x;
    x1.y = v.y * ah * aw.y;
    x1.z = v.z * ah * aw.z;
    x1.w = v.w * ah * aw.w;
    float csum = x1.x + x1.y + x1.z + x1.w;
    s1 += csum;
    s2 = fmaf(x1.x, x1.x, s2); s2 = fmaf(x1.y, x1.y, s2);
    s2 = fmaf(x1.z, x1.z, s2); s2 = fmaf(x1.w, x1.w, s2);
    float cw = wred(csum);
    if (lane == 0) chpart[k*16 + wv] = cw;
  }
  float r1 = wred(s1), r2 = wred(s2);
  if (lane == 0){ red1[wv] = r1; red2[wv] = r2; }
  __syncthreads();
  if (tid == 0){
    float S = 0.f, SS = 0.f;
#pragma unroll
    for (int i = 0; i < 16; ++i){ S += red1[i]; SS += red2[i]; }
    float mu = S * (1.f/65536.f);
    float var = SS * (1.f/65536.f) - mu*mu;
    murs[0] = mu; murs[1] = rsqrtf(var + 1e-5f);
  }
  __syncthreads();
  if (tid < 16){
    float ch = 0.f;
#pragma unroll
    for (int m = 0; m < 16; ++m) ch += chpart[tid*16 + m];
    float mu = murs[0], rstd = murs[1];
    float g = gnw[tid], b = gnb[tid];
    float sc = rstd * g;
    sc_s[tid] = sc; of_s[tid] = b - mu*sc;
    v2_s[tid] = (ch * (1.f/4096.f) - mu) * sc + b;   // V2
  }
  __syncthreads();

  // ---- pass B: Z2 per channel; keep exp(x2) bf16-packed in regs ----
  unsigned e2a[16], e2b[16];
#pragma unroll 2
  for (int k = 0; k < 16; ++k){
    float4 v = x4[k*1024 + tid];
    float ah = ahs[k*64 + h];
    float4 aw = aws4[k*16 + w4];
    float sc = sc_s[k], of = of_s[k];
    float ex = __expf(fmaf(v.x * ah * aw.x, sc, of));
    float ey = __expf(fmaf(v.y * ah * aw.y, sc, of));
    float ez = __expf(fmaf(v.z * ah * aw.z, sc, of));
    float ew = __expf(fmaf(v.w * ah * aw.w, sc, of));
    float z = ex + ey + ez + ew;
    e2a[k] = (unsigned)f2b(ex) | ((unsigned)f2b(ey) << 16);
    e2b[k] = (unsigned)f2b(ez) | ((unsigned)f2b(ew) << 16);
    float zw = wred(z);
    if (lane == 0) zpart[k*16 + wv] = zw;
  }
  __syncthreads();
  if (tid < 16){
    float z2 = 0.f;
#pragma unroll
    for (int m = 0; m < 16; ++m) z2 += zpart[tid*16 + m];
    float v3 = 0.f, z3 = 0.f;
#pragma unroll
    for (int ss = 0; ss < 8; ++ss){
      v3 += V3part[((size_t)bg*8 + ss)*16 + tid];
      z3 += Z3part[((size_t)bg*8 + ss)*16 + tid];
    }
    p2s[tid] = v3 * (1.f/4096.f) / z2;   // multiplies exp(x2):  V3 * A2
    p3s[tid] = v2_s[tid] / z3;           // multiplies exp(x3):  V2 * A3
  }
  __syncthreads();

  // ---- pass C: t from register exp(x2) + global E3 (no x re-read) ----
  float4 tacc = make_float4(0.f,0.f,0.f,0.f);
#pragma unroll 4
  for (int k = 0; k < 16; ++k){
    ushort4 eu = E34[k*1024 + tid];
    float p2 = p2s[k], p3 = p3s[k];
    tacc.x += bf2f((unsigned short)(e2a[k] & 0xffffu))*p2 + bf2f(eu.x)*p3;
    tacc.y += bf2f((unsigned short)(e2a[k] >> 16))   *p2 + bf2f(eu.y)*p3;
    tacc.z += bf2f((unsigned short)(e2b[k] & 0xffffu))*p2 + bf2f(eu.z)*p3;
    tacc.w += bf2f((unsigned short)(e2b[k] >> 16))   *p2 + bf2f(eu.w)*p3;
  }
  float4 e;
  e.x = __expf(tacc.x); e.y = __expf(tacc.y);
  e.z = __expf(tacc.z); e.w = __expf(tacc.w);
  float es = e.x + e.y + e.z + e.w;
  float rr = wred(es);
  if (lane == 0) red1[wv] = rr;
  __syncthreads();
  if (tid == 0){
    float S = 0.f;
#pragma unroll
    for (int i = 0; i < 16; ++i) S += red1[i];
    invS_s = 1.f / S;
  }
  __syncthreads();
  float iS = invS_s;
  float4 ei = make_float4(e.x*iS, e.y*iS, e.z*iS, e.w*iS);

  // ---- pass D: out = x * s ----
#pragma unroll 4
  for (int k = 0; k < 16; ++k){
    float4 v = x4[k*1024 + tid];
    float4 ov;
    ov.x = v.x * ei.x; ov.y = v.y * ei.y;
    ov.z = v.z * ei.z; ov.w = v.w * ei.w;
    o4[k*1024 + tid] = ov;
  }
}

extern "C" void kernel_launch(void* const* d_in, const int* in_sizes, int n_in,
                              void* d_out, int out_size, void* d_ws, size_t ws_size,
                              hipStream_t stream)
{
  const float* x   = (const float*)d_in[0];
  const float* w1  = (const float*)d_in[1];
  const float* b1  = (const float*)d_in[2];
  const float* wh  = (const float*)d_in[3];
  const float* bh  = (const float*)d_in[4];
  const float* ww  = (const float*)d_in[5];
  const float* bw  = (const float*)d_in[6];
  const float* w3  = (const float*)d_in[7];
  const float* b3  = (const float*)d_in[8];
  const float* gnw = (const float*)d_in[9];
  const float* gnb = (const float*)d_in[10];
  float* out = (float*)d_out;

  float* V3part = (float*)d_ws;                        // 65536 floats
  float* Z3part = V3part + 65536;                      // 65536 floats
  float* rs_g   = Z3part + 65536;                      // 512*16*64   = 524288 floats
  float* csp_g  = rs_g + 524288;                       // 512*8*16*64 = 4194304 floats
  __hip_bfloat16* E3 = (__hip_bfloat16*)(csp_g + 4194304);  // 33554432 bf16 (64 MB)
  (void)ws_size; (void)n_in; (void)in_sizes; (void)out_size;

  k3_conv<<<dim3(8, 512), 256, 0, stream>>>(x, w3, b3, E3, V3part, Z3part,
                                            rs_g, csp_g);
  mega   <<<512, 1024, 0, stream>>>(x, w1, b1, wh, bh, ww, bw, gnw, gnb,
                                    V3part, Z3part, rs_g, csp_g, E3, out);
}

// Round 8
// 1088.091 us; speedup vs baseline: 1.1306x; 1.1306x over previous
//
#include <hip/hip_runtime.h>
#include <hip/hip_bf16.h>

#define CHW  65536   // 16 ch * 64 * 64 per bg-group
#define CHW4 16384   // in float4

__device__ __forceinline__ float wred(float v){
#pragma unroll
  for (int o = 32; o; o >>= 1) v += __shfl_xor(v, o, 64);
  return v;
}
__device__ __forceinline__ float bf2f(unsigned short u){
  return __uint_as_float(((unsigned)u) << 16);
}
__device__ __forceinline__ unsigned short f2b(float f){
  union { __hip_bfloat16 h; unsigned short u; } cv;
  cv.h = __float2bfloat16(f);
  return cv.u;
}

// ---------------- K3: 3x3 grouped conv, ZERO LDS ----------------------------
// Each thread computes 8 px of one output row for 4 co; inputs loaded direct
// from global (L1/L2-served; conflict-free, proven R7).  Per row only the 10
// needed columns are loaded (scalar edges + two float4) -> 30 live dest regs
// (was 48, which spilled under the 102-reg cap).  launch_bounds(256,4) gives
// a 128-reg budget.  Also emits pooled row/col partials + V3/Z3 + E3.
__global__ __launch_bounds__(256, 4) void k3_conv(const float* __restrict__ x,
    const float* __restrict__ w3, const float* __restrict__ b3,
    __hip_bfloat16* __restrict__ E3,
    float* __restrict__ V3part, float* __restrict__ Z3part,
    float* __restrict__ rs_g, float* __restrict__ csp_g)
{
  int tid = threadIdx.x;
  int st  = blockIdx.x;      // stripe 0..7
  int bg  = blockIdx.y;
  size_t base  = (size_t)bg * CHW;
  const float* xf = x + base;
  int lane = tid & 63;
  int cog = __builtin_amdgcn_readfirstlane(tid >> 6);  // wave-uniform co group
  int co0 = cog * 4;
  int r  = lane >> 3;          // output row within stripe
  int cc = lane & 7;           // 8-px col chunk
  int h0 = st*8 + r;           // output row in image
  int w0 = cc*8;               // first output col

  float acc[4][8];
#pragma unroll
  for (int i = 0; i < 4; ++i)
#pragma unroll
    for (int px = 0; px < 8; ++px) acc[i][px] = 0.f;

  const float4 z4 = make_float4(0.f, 0.f, 0.f, 0.f);

#pragma unroll 1
  for (int ci = 0; ci < 16; ++ci){
    const float* cib = xf + ci*4096;
    // ---- loads: 3 rows x 10 needed cols (w0-1 .. w0+8) ----
    float  eL[3], eH[3];
    float4 A[3], Bv[3];
#pragma unroll
    for (int dy = 0; dy < 3; ++dy){
      int hh = h0 - 1 + dy;
      bool rok = (unsigned)hh < 64u;
      const float* rb = cib + hh*64;
      eL[dy] = (rok && cc > 0) ? rb[w0-1] : 0.f;
      A[dy]  = rok ? *(const float4*)(rb + w0)     : z4;
      Bv[dy] = rok ? *(const float4*)(rb + w0 + 4) : z4;
      eH[dy] = (rok && cc < 7) ? rb[w0+8] : 0.f;
    }
    // ---- weights (wave-uniform -> scalar loads) ----
    float wgt[4][9];
#pragma unroll
    for (int i = 0; i < 4; ++i)
#pragma unroll
      for (int t = 0; t < 9; ++t)
        wgt[i][t] = w3[((co0+i)*16 + ci)*9 + t];
    // ---- FMAs ----
#pragma unroll
    for (int dy = 0; dy < 3; ++dy){
      float v[10] = {eL[dy], A[dy].x, A[dy].y, A[dy].z, A[dy].w,
                     Bv[dy].x, Bv[dy].y, Bv[dy].z, Bv[dy].w, eH[dy]};
#pragma unroll
      for (int dx = 0; dx < 3; ++dx){
#pragma unroll
        for (int px = 0; px < 8; ++px){
          float iv = v[px + dx];
#pragma unroll
          for (int i = 0; i < 4; ++i)
            acc[i][px] = fmaf(wgt[i][dy*3+dx], iv, acc[i][px]);
        }
      }
    }
    // ---- pooled partials from center-row registers (wave ci&3 owns ci) ----
    if (cog == (ci & 3)){
      float sm = A[1].x+A[1].y+A[1].z+A[1].w
               + Bv[1].x+Bv[1].y+Bv[1].z+Bv[1].w;
      sm += __shfl_xor(sm, 1, 64);
      sm += __shfl_xor(sm, 2, 64);
      sm += __shfl_xor(sm, 4, 64);
      if (cc == 0) rs_g[(size_t)bg*1024 + ci*64 + h0] = sm;
      float4 ca = A[1], cb = Bv[1];
#pragma unroll
      for (int o = 8; o < 64; o <<= 1){
        ca.x += __shfl_xor(ca.x, o, 64); ca.y += __shfl_xor(ca.y, o, 64);
        ca.z += __shfl_xor(ca.z, o, 64); ca.w += __shfl_xor(ca.w, o, 64);
        cb.x += __shfl_xor(cb.x, o, 64); cb.y += __shfl_xor(cb.y, o, 64);
        cb.z += __shfl_xor(cb.z, o, 64); cb.w += __shfl_xor(cb.w, o, 64);
      }
      if (r == 0){
        float* cp = &csp_g[((size_t)(bg*8 + st)*16 + ci)*64 + cc*8];
        *(float4*)&cp[0] = ca;
        *(float4*)&cp[4] = cb;
      }
    }
  }

  // ---- epilogue: relu/exp -> E3 bf16, V3/Z3 stripe partials ----
#pragma unroll
  for (int i = 0; i < 4; ++i){
    float bias = b3[co0+i];
    union { unsigned short hb[8]; uint4 u; } pk;
    float v3acc = 0.f, z3acc = 0.f;
#pragma unroll
    for (int px = 0; px < 8; ++px){
      float val = fmaxf(acc[i][px] + bias, 0.f);   // x3
      float e = __expf(val);
      v3acc += val;
      z3acc += e;
      pk.hb[px] = f2b(e);
    }
    *(uint4*)&E3[base + (size_t)(co0+i)*4096 + h0*64 + cc*8] = pk.u;
    float rv = wred(v3acc);
    float rz = wred(z3acc);
    if (lane == 0){
      V3part[((size_t)bg*8 + st)*16 + co0 + i] = rv;
      Z3part[((size_t)bg*8 + st)*16 + co0 + i] = rz;
    }
  }
}

// ---------------- MEGA: attention maps + stats + t softmax + out ------------
// pass0 x-sweep replaced by reading k3's pooled partials; passC reads no x
// (exp(x2) carried bf16-packed in registers from passB).
__global__ __launch_bounds__(1024, 8) void mega(const float* __restrict__ x,
    const float* __restrict__ w1, const float* __restrict__ b1,
    const float* __restrict__ wh, const float* __restrict__ bh,
    const float* __restrict__ ww, const float* __restrict__ bw,
    const float* __restrict__ gnw, const float* __restrict__ gnb,
    const float* __restrict__ V3part, const float* __restrict__ Z3part,
    const float* __restrict__ rs_g, const float* __restrict__ csp_g,
    const __hip_bfloat16* __restrict__ E3,
    float* __restrict__ out)
{
  __shared__ float rs[1024];                 // rowsum[ch*64+h]
  __shared__ float cs[1024];                 // colsum[ch*64+w]
  __shared__ float ym[2048];
  __shared__ __align__(16) float ahs[1024], aws[1024];
  __shared__ float chpart[256], zpart[256];
  __shared__ float red1[16], red2[16];
  __shared__ float murs[2];
  __shared__ float sc_s[16], of_s[16], v2_s[16], p2s[16], p3s[16];
  __shared__ float invS_s;

  int tid = threadIdx.x, bg = blockIdx.x;
  const float4* x4 = (const float4*)x + (size_t)bg * CHW4;
  const ushort4* E34 = (const ushort4*)E3 + (size_t)bg * CHW4;
  float4* o4 = (float4*)out + (size_t)bg * CHW4;
  int h = tid >> 4, w4 = tid & 15, lane = tid & 63, wv = tid >> 6;

  // ---- pass 0': pooled sums from k3 partials (no x sweep) ----
  rs[tid] = rs_g[(size_t)bg*1024 + tid];
  {
    const float* cp = csp_g + (size_t)bg*8192;
    float csum = 0.f;
#pragma unroll
    for (int ss = 0; ss < 8; ++ss) csum += cp[ss*1024 + tid];
    cs[tid] = csum;
  }
  __syncthreads();
  // y = relu(w1 @ [rowmean|colmean] + b1)
  for (int ol = tid; ol < 2048; ol += 1024){
    int o = ol >> 7, l = ol & 127;
    float acc = b1[o];
#pragma unroll
    for (int i = 0; i < 16; ++i){
      float mv = (l < 64 ? rs[i*64 + l] : cs[i*64 + (l-64)]) * (1.f/64.f);
      acc = fmaf(w1[o*16 + i], mv, acc);
    }
    ym[o*128 + l] = fmaxf(acc, 0.f);
  }
  __syncthreads();
  for (int ol = tid; ol < 2048; ol += 1024){
    int q = ol >> 10;             // 0 -> a_h, 1 -> a_w
    int o = (ol >> 6) & 15;
    int p = ol & 63;
    const float* Wm = q ? ww : wh;
    float acc = q ? bw[o] : bh[o];
#pragma unroll
    for (int i = 0; i < 16; ++i)
      acc = fmaf(Wm[o*16 + i], ym[i*128 + q*64 + p], acc);
    float sg = 1.f / (1.f + __expf(-acc));
    (q ? aws : ahs)[o*64 + p] = sg;
  }
  __syncthreads();

  // ---- pass A: mu/var + per-channel sums ----
  const float4* aws4 = (const float4*)aws;
  float s1 = 0.f, s2 = 0.f;
#pragma unroll 4
  for (int k = 0; k < 16; ++k){
    float4 v = x4[k*1024 + tid];
    float ah = ahs[k*64 + h];
    float4 aw = aws4[k*16 + w4];
    float4 x1;
    x1.x = v.x * ah * aw.x;
    x1.y = v.y * ah * aw.y;
    x1.z = v.z * ah * aw.z;
    x1.w = v.w * ah * aw.w;
    float csum = x1.x + x1.y + x1.z + x1.w;
    s1 += csum;
    s2 = fmaf(x1.x, x1.x, s2); s2 = fmaf(x1.y, x1.y, s2);
    s2 = fmaf(x1.z, x1.z, s2); s2 = fmaf(x1.w, x1.w, s2);
    float cw = wred(csum);
    if (lane == 0) chpart[k*16 + wv] = cw;
  }
  float r1 = wred(s1), r2 = wred(s2);
  if (lane == 0){ red1[wv] = r1; red2[wv] = r2; }
  __syncthreads();
  if (tid == 0){
    float S = 0.f, SS = 0.f;
#pragma unroll
    for (int i = 0; i < 16; ++i){ S += red1[i]; SS += red2[i]; }
    float mu = S * (1.f/65536.f);
    float var = SS * (1.f/65536.f) - mu*mu;
    murs[0] = mu; murs[1] = rsqrtf(var + 1e-5f);
  }
  __syncthreads();
  if (tid < 16){
    float ch = 0.f;
#pragma unroll
    for (int m = 0; m < 16; ++m) ch += chpart[tid*16 + m];
    float mu = murs[0], rstd = murs[1];
    float g = gnw[tid], b = gnb[tid];
    float sc = rstd * g;
    sc_s[tid] = sc; of_s[tid] = b - mu*sc;
    v2_s[tid] = (ch * (1.f/4096.f) - mu) * sc + b;   // V2
  }
  __syncthreads();

  // ---- pass B: Z2 per channel; keep exp(x2) bf16-packed in regs ----
  unsigned e2a[16], e2b[16];
#pragma unroll 2
  for (int k = 0; k < 16; ++k){
    float4 v = x4[k*1024 + tid];
    float ah = ahs[k*64 + h];
    float4 aw = aws4[k*16 + w4];
    float sc = sc_s[k], of = of_s[k];
    float ex = __expf(fmaf(v.x * ah * aw.x, sc, of));
    float ey = __expf(fmaf(v.y * ah * aw.y, sc, of));
    float ez = __expf(fmaf(v.z * ah * aw.z, sc, of));
    float ew = __expf(fmaf(v.w * ah * aw.w, sc, of));
    float z = ex + ey + ez + ew;
    e2a[k] = (unsigned)f2b(ex) | ((unsigned)f2b(ey) << 16);
    e2b[k] = (unsigned)f2b(ez) | ((unsigned)f2b(ew) << 16);
    float zw = wred(z);
    if (lane == 0) zpart[k*16 + wv] = zw;
  }
  __syncthreads();
  if (tid < 16){
    float z2 = 0.f;
#pragma unroll
    for (int m = 0; m < 16; ++m) z2 += zpart[tid*16 + m];
    float v3 = 0.f, z3 = 0.f;
#pragma unroll
    for (int ss = 0; ss < 8; ++ss){
      v3 += V3part[((size_t)bg*8 + ss)*16 + tid];
      z3 += Z3part[((size_t)bg*8 + ss)*16 + tid];
    }
    p2s[tid] = v3 * (1.f/4096.f) / z2;   // multiplies exp(x2):  V3 * A2
    p3s[tid] = v2_s[tid] / z3;           // multiplies exp(x3):  V2 * A3
  }
  __syncthreads();

  // ---- pass C: t from register exp(x2) + global E3 (no x re-read) ----
  float4 tacc = make_float4(0.f,0.f,0.f,0.f);
#pragma unroll 4
  for (int k = 0; k < 16; ++k){
    ushort4 eu = E34[k*1024 + tid];
    float p2 = p2s[k], p3 = p3s[k];
    tacc.x += bf2f((unsigned short)(e2a[k] & 0xffffu))*p2 + bf2f(eu.x)*p3;
    tacc.y += bf2f((unsigned short)(e2a[k] >> 16))   *p2 + bf2f(eu.y)*p3;
    tacc.z += bf2f((unsigned short)(e2b[k] & 0xffffu))*p2 + bf2f(eu.z)*p3;
    tacc.w += bf2f((unsigned short)(e2b[k] >> 16))   *p2 + bf2f(eu.w)*p3;
  }
  float4 e;
  e.x = __expf(tacc.x); e.y = __expf(tacc.y);
  e.z = __expf(tacc.z); e.w = __expf(tacc.w);
  float es = e.x + e.y + e.z + e.w;
  float rr = wred(es);
  if (lane == 0) red1[wv] = rr;
  __syncthreads();
  if (tid == 0){
    float S = 0.f;
#pragma unroll
    for (int i = 0; i < 16; ++i) S += red1[i];
    invS_s = 1.f / S;
  }
  __syncthreads();
  float iS = invS_s;
  float4 ei = make_float4(e.x*iS, e.y*iS, e.z*iS, e.w*iS);

  // ---- pass D: out = x * s ----
#pragma unroll 4
  for (int k = 0; k < 16; ++k){
    float4 v = x4[k*1024 + tid];
    float4 ov;
    ov.x = v.x * ei.x; ov.y = v.y * ei.y;
    ov.z = v.z * ei.z; ov.w = v.w * ei.w;
    o4[k*1024 + tid] = ov;
  }
}

extern "C" void kernel_launch(void* const* d_in, const int* in_sizes, int n_in,
                              void* d_out, int out_size, void* d_ws, size_t ws_size,
                              hipStream_t stream)
{
  const float* x   = (const float*)d_in[0];
  const float* w1  = (const float*)d_in[1];
  const float* b1  = (const float*)d_in[2];
  const float* wh  = (const float*)d_in[3];
  const float* bh  = (const float*)d_in[4];
  const float* ww  = (const float*)d_in[5];
  const float* bw  = (const float*)d_in[6];
  const float* w3  = (const float*)d_in[7];
  const float* b3  = (const float*)d_in[8];
  const float* gnw = (const float*)d_in[9];
  const float* gnb = (const float*)d_in[10];
  float* out = (float*)d_out;

  float* V3part = (float*)d_ws;                        // 65536 floats
  float* Z3part = V3part + 65536;                      // 65536 floats
  float* rs_g   = Z3part + 65536;                      // 512*16*64   = 524288 floats
  float* csp_g  = rs_g + 524288;                       // 512*8*16*64 = 4194304 floats
  __hip_bfloat16* E3 = (__hip_bfloat16*)(csp_g + 4194304);  // 33554432 bf16 (64 MB)
  (void)ws_size; (void)n_in; (void)in_sizes; (void)out_size;

  k3_conv<<<dim3(8, 512), 256, 0, stream>>>(x, w3, b3, E3, V3part, Z3part,
                                            rs_g, csp_g);
  mega   <<<512, 1024, 0, stream>>>(x, w1, b1, wh, bh, ww, bw, gnw, gnb,
                                    V3part, Z3part, rs_g, csp_g, E3, out);
}